// Round 1
// 86.459 us; speedup vs baseline: 1.1443x; 1.1443x over previous
//
#include <hip/hip_runtime.h>
#include <math.h>

#define Bn   2
#define En   2048
#define N1n  96
#define Kn   32
#define CINn 64
#define CBn  32
#define On   64
#define Gn   4
#define Fn   160   // 2*CIN + CB
#define NEG  0.01f
#define NW   8          // waves per block
#define NT   (NW * 64)  // 512 threads
#define EB   2          // edges batched per wave per Weff sweep
#define SUBn 4          // sub-blocks per (b,k2) bucket
#define ELCAP 256       // elist capacity per sub-block (mean 16, huge margin)

// ---------------------------------------------------------------------------
// R3: parallelism split. R2 used 64 blocks on a 256-CU chip (75% idle) and
// each bucket was one latency chain. Now 4 sub-blocks per (b,k2) bucket
// (grid=256), partitioned by the DETERMINISTIC predicate (e & 3) == sub
// (position-based partitioning would race: elist order is atomic-dependent
// and differs between the sub-blocks of one bucket). Each sub-block writes
// a 64-float partial into d_ws; a tiny second kernel sums the 4 partials
// deterministically. EB drops 8->2 (16 edges/sub-block), LDS 76KB->50KB.
// Math per edge is byte-identical to the harness-verified R2 kernel.
// ---------------------------------------------------------------------------
__global__ void __launch_bounds__(NT, 1)
fused_kernel(const float* __restrict__ sites1, const float* __restrict__ sites2,
             const float* __restrict__ bonds,  const float* __restrict__ W_eq,
             const float* __restrict__ b_eq,   const float* __restrict__ W_att,
             const float* __restrict__ b_att,  const int* __restrict__ idx1,
             const int* __restrict__ idx2,     const int* __restrict__ perms1,
             const int* __restrict__ perms2,   float* __restrict__ ws) {
    __shared__ float Weff[Fn][On];       // 40960 B
    __shared__ float vs[NW][EB][96];     //  6144 B
    __shared__ float red[NW][On];        //  2048 B
    __shared__ float s2[CINn];           //   256 B
    __shared__ float wgs[Gn];
    __shared__ int   elist[ELCAP];       //  1024 B
    __shared__ int   ecount;

    const int t      = threadIdx.x;
    const int bucket = blockIdx.x >> 2;  // (b,k2)
    const int sub    = blockIdx.x & (SUBn - 1);
    const int b      = bucket >> 5;      // Kn = 32
    const int k2     = bucket & (Kn - 1);

    // group weights w_g(k2) = [perms1[g, j] == k2] where perms2[g, j] == k2
    if (t < Gn) {
        int g = t, j = 0;
        for (; j < Kn; ++j) if (perms2[g * Kn + j] == k2) break;
        wgs[g] = (j < Kn && perms1[g * Kn + j] == k2) ? 1.f : 0.f;
    }
    if (t == Gn) ecount = 0;
    __syncthreads();

    // stage Weff[k2] into LDS (float4-wise, coalesced; W_eq is L2-hot)
    {
        const float w0 = wgs[0], w1 = wgs[1], w2 = wgs[2], w3 = wgs[3];
        const float4* W4 = (const float4*)W_eq;
        float4* Wd = (float4*)&Weff[0][0];
        const int n4 = Fn * On / 4;      // 2560 float4 per group
#pragma unroll
        for (int i = t; i < n4; i += NT) {
            float4 a0 = W4[i], a1 = W4[n4 + i], a2 = W4[2 * n4 + i], a3 = W4[3 * n4 + i];
            float4 r;
            r.x = 0.25f * (w0 * a0.x + w1 * a1.x + w2 * a2.x + w3 * a3.x);
            r.y = 0.25f * (w0 * a0.y + w1 * a1.y + w2 * a2.y + w3 * a3.y);
            r.z = 0.25f * (w0 * a0.z + w1 * a1.z + w2 * a2.z + w3 * a3.z);
            r.w = 0.25f * (w0 * a0.w + w1 * a1.w + w2 * a2.w + w3 * a3.w);
            Wd[i] = r;
        }
    }

    // build this sub-block's edge list: idx2[e]==k2 AND (e&3)==sub
    for (int e = t; e < En; e += NT)
        if (idx2[e] == k2 && (e & (SUBn - 1)) == sub) {
            int p = atomicAdd(&ecount, 1);
            elist[p] = e;
        }

    // sites2 row (shared by every edge in the bucket)
    if (t < CINn) s2[t] = sites2[(b * Kn + k2) * CINn + t];
    __syncthreads();

    const int w    = t >> 6;
    const int lane = t & 63;
    const int og   = lane & 15;          // output quad: o = 4*og .. 4*og+3
    const int fg   = lane >> 4;          // f stripe: f ≡ fg (mod 4)
    const int ec   = ecount;

    const float4 be4 = ((const float4*)b_eq)[og];
    const float4 wa  = ((const float4*)W_att)[og];
    const float  ba  = b_att[0];

    // shared sites2 partial: p2 = sum_{f in [64,128)} s2[f-64] * Weff[f][4og..]
    float4 p2 = make_float4(0.f, 0.f, 0.f, 0.f);
#pragma unroll
    for (int fi = 0; fi < 16; ++fi) {
        const int f  = 64 + 4 * fi + fg;
        const float  vf = s2[4 * fi + fg];
        const float4 wv = *(const float4*)&Weff[f][og * 4];
        p2.x += vf * wv.x; p2.y += vf * wv.y;
        p2.z += vf * wv.z; p2.w += vf * wv.w;
    }

    float4 oacc = make_float4(0.f, 0.f, 0.f, 0.f);

    for (int base = w * EB; base < ec; base += NW * EB) {
        const int nb = (ec - base < EB) ? (ec - base) : EB;

        // stage this batch's varying v entries: [sites1 row | bonds row]
        __builtin_amdgcn_wave_barrier();
#pragma unroll
        for (int j = 0; j < EB; ++j) {
            const int jj = j < nb ? j : nb - 1;    // clamp: pads reuse a valid edge
            const int e  = elist[base + jj];
            const int i1 = idx1[e];
            vs[w][j][lane] = sites1[((b * N1n + i1) << 6) + lane];
            if (lane < CBn) vs[w][j][CINn + lane] = bonds[(b * En + e) * CBn + lane];
        }
        __builtin_amdgcn_wave_barrier();

        float4 acc[EB];
#pragma unroll
        for (int j = 0; j < EB; ++j) acc[j] = p2;

        // matvec over the 96 varying f's; each Weff b128 feeds all EB edges
#pragma unroll
        for (int fi = 0; fi < 24; ++fi) {
            const int vsidx = 4 * fi + fg;
            const int f     = vsidx < CINn ? vsidx : vsidx + CINn;  // skip s2 band
            const float4 wv = *(const float4*)&Weff[f][og * 4];
#pragma unroll
            for (int j = 0; j < EB; ++j) {
                const float vf = vs[w][j][vsidx];
                acc[j].x += vf * wv.x; acc[j].y += vf * wv.y;
                acc[j].z += vf * wv.z; acc[j].w += vf * wv.w;
            }
        }
        __builtin_amdgcn_wave_barrier();

        // per-edge epilogue
#pragma unroll
        for (int j = 0; j < EB; ++j) {
            float4 a = acc[j];
#pragma unroll
            for (int m = 16; m <= 32; m <<= 1) {     // reduce the 4 f stripes
                a.x += __shfl_xor(a.x, m);
                a.y += __shfl_xor(a.y, m);
                a.z += __shfl_xor(a.z, m);
                a.w += __shfl_xor(a.w, m);
            }
            float4 lat;
            lat.x = a.x + be4.x; lat.x = lat.x > 0.f ? lat.x : NEG * lat.x;
            lat.y = a.y + be4.y; lat.y = lat.y > 0.f ? lat.y : NEG * lat.y;
            lat.z = a.z + be4.z; lat.z = lat.z > 0.f ? lat.z : NEG * lat.z;
            lat.w = a.w + be4.w; lat.w = lat.w > 0.f ? lat.w : NEG * lat.w;

            float part = lat.x * wa.x + lat.y * wa.y + lat.z * wa.z + lat.w * wa.w;
#pragma unroll
            for (int m = 1; m <= 8; m <<= 1) part += __shfl_xor(part, m);

            float att = 1.f / (1.f + expf(-(part + ba)));
            att *= (j < nb) ? 1.f : 0.f;             // mask clamp-padded edges
            oacc.x += att * lat.x;
            oacc.y += att * lat.y;
            oacc.z += att * lat.z;
            oacc.w += att * lat.w;
        }
    }

    if (fg == 0) *(float4*)&red[w][og * 4] = oacc;
    __syncthreads();

    // write this sub-block's 64-float partial into workspace
    if (t < On) {
        float s = 0.f;
#pragma unroll
        for (int q = 0; q < NW; ++q) s += red[q][t];
        ws[((size_t)bucket * SUBn + sub) * On + t] = s;
    }
}

// ---------------------------------------------------------------------------
// deterministic cross-sub reduction: out[bucket][o] = sum_sub ws[bucket][sub][o]
__global__ void __launch_bounds__(256)
reduce_kernel(const float* __restrict__ ws, float* __restrict__ out) {
    const int i = blockIdx.x * 256 + threadIdx.x;   // 0 .. Bn*Kn*On-1
    const int bucket = i >> 6;
    const int o      = i & (On - 1);
    const float* p = ws + (size_t)bucket * SUBn * On + o;
    out[i] = (p[0] + p[On]) + (p[2 * On] + p[3 * On]);
}

// ---------------------------------------------------------------------------
extern "C" void kernel_launch(void* const* d_in, const int* in_sizes, int n_in,
                              void* d_out, int out_size, void* d_ws, size_t ws_size,
                              hipStream_t stream) {
    const float* sites1 = (const float*)d_in[0];
    const float* sites2 = (const float*)d_in[1];
    const float* bonds  = (const float*)d_in[2];
    const float* W_eq   = (const float*)d_in[3];
    const float* b_eq   = (const float*)d_in[4];
    const float* W_att  = (const float*)d_in[5];
    const float* b_att  = (const float*)d_in[6];
    /* d_in[7] = idx2_oh (unused — reduced algebraically) */
    const int*   idx1   = (const int*)d_in[8];
    const int*   idx2   = (const int*)d_in[9];
    const int*   perms1 = (const int*)d_in[10];
    const int*   perms2 = (const int*)d_in[11];
    float* out = (float*)d_out;
    float* ws  = (float*)d_ws;

    fused_kernel<<<Bn * Kn * SUBn, NT, 0, stream>>>(
        sites1, sites2, bonds, W_eq, b_eq, W_att, b_att,
        idx1, idx2, perms1, perms2, ws);
    reduce_kernel<<<(Bn * Kn * On) / 256, 256, 0, stream>>>(ws, out);
}

// Round 2
// 84.581 us; speedup vs baseline: 1.1697x; 1.0222x over previous
//
#include <hip/hip_runtime.h>
#include <math.h>

#define Bn   2
#define En   2048
#define N1n  96
#define Kn   32
#define CINn 64
#define CBn  32
#define On   64
#define Gn   4
#define Fn   160   // 2*CIN + CB
#define NEG  0.01f
#define NW   8          // waves per block
#define NT   (NW * 64)  // 512 threads
#define EB   2          // edges batched per wave per Weff sweep
#define SUBn 8          // sub-blocks per (b,k2) bucket
#define ELCAP 128       // elist capacity per sub-block (mean 4, huge margin)

// ---------------------------------------------------------------------------
// R4: kill the fixed-cost latency chains (the main loop is now only ~4-8
// edges/block, so per-block prologue latency dominates).
//  * wgs: perms2[g] is a permutation of 0..K-1, so the j with
//    perms2[g][j]==k2 is unique -> wgs[g]=1 iff some t in [0,128) has
//    perms2[t]==k2 && perms1[t]==k2. One L2 round-trip replaces the old
//    32-iteration serial probe loop (which stalled the whole block ~3us).
//    Done entirely inside wave 0 (wave-synchronous; no extra barrier).
//  * SUBn 4->8, grid 512 = 2 blocks/CU (__launch_bounds__(512,4), LDS
//    50KB*2 < 160KB): two independent latency chains per CU overlap.
//  * elist scan issued BEFORE Weff staging: both independent load groups
//    are in flight together instead of back-to-back.
// Per-edge math byte-identical to the harness-verified R3 kernel; only the
// partial-sum grouping changes (8 deterministic partials per bucket).
// ---------------------------------------------------------------------------
__global__ void __launch_bounds__(NT, 4)
fused_kernel(const float* __restrict__ sites1, const float* __restrict__ sites2,
             const float* __restrict__ bonds,  const float* __restrict__ W_eq,
             const float* __restrict__ b_eq,   const float* __restrict__ W_att,
             const float* __restrict__ b_att,  const int* __restrict__ idx1,
             const int* __restrict__ idx2,     const int* __restrict__ perms1,
             const int* __restrict__ perms2,   float* __restrict__ ws) {
    __shared__ float Weff[Fn][On];       // 40960 B
    __shared__ float vs[NW][EB][96];     //  6144 B
    __shared__ float red[NW][On];        //  2048 B
    __shared__ float s2[CINn];           //   256 B
    __shared__ float wgs[Gn];
    __shared__ int   elist[ELCAP];       //   512 B
    __shared__ int   ecount;

    const int t      = threadIdx.x;
    const int bucket = blockIdx.x >> 3;  // (b,k2)
    const int sub    = blockIdx.x & (SUBn - 1);
    const int b      = bucket >> 5;      // Kn = 32
    const int k2     = bucket & (Kn - 1);

    // wgs[g] = [perms1[g,j]==k2] at the unique j where perms2[g,j]==k2.
    // All done by wave 0 (wave-synchronous LDS ordering; no barrier needed
    // between the zero-init and the conditional writes).
    if (t < Gn) wgs[t] = 0.f;
    __builtin_amdgcn_wave_barrier();
    if (t < 64) {
        const int pa2 = perms2[t],      pa1 = perms1[t];
        const int pb2 = perms2[t + 64], pb1 = perms1[t + 64];
        if (pa2 == k2 && pa1 == k2) wgs[t >> 5] = 1.f;
        if (pb2 == k2 && pb1 == k2) wgs[(t + 64) >> 5] = 1.f;
    }
    if (t == 64) ecount = 0;             // wave 1, independent of wgs
    __syncthreads();

    // build this sub-block's edge list first: its idx2 loads overlap the
    // Weff staging loads issued just below (independent latency groups)
    for (int e = t; e < En; e += NT)
        if (idx2[e] == k2 && (e & (SUBn - 1)) == sub) {
            int p = atomicAdd(&ecount, 1);
            elist[p] = e;
        }

    // stage Weff[k2] into LDS (float4-wise, coalesced; W_eq is L2-hot)
    {
        const float w0 = wgs[0], w1 = wgs[1], w2 = wgs[2], w3 = wgs[3];
        const float4* W4 = (const float4*)W_eq;
        float4* Wd = (float4*)&Weff[0][0];
        const int n4 = Fn * On / 4;      // 2560 float4 per group
#pragma unroll
        for (int i = t; i < n4; i += NT) {
            float4 a0 = W4[i], a1 = W4[n4 + i], a2 = W4[2 * n4 + i], a3 = W4[3 * n4 + i];
            float4 r;
            r.x = 0.25f * (w0 * a0.x + w1 * a1.x + w2 * a2.x + w3 * a3.x);
            r.y = 0.25f * (w0 * a0.y + w1 * a1.y + w2 * a2.y + w3 * a3.y);
            r.z = 0.25f * (w0 * a0.z + w1 * a1.z + w2 * a2.z + w3 * a3.z);
            r.w = 0.25f * (w0 * a0.w + w1 * a1.w + w2 * a2.w + w3 * a3.w);
            Wd[i] = r;
        }
    }

    // sites2 row (shared by every edge in the bucket)
    if (t < CINn) s2[t] = sites2[(b * Kn + k2) * CINn + t];
    __syncthreads();

    const int w    = t >> 6;
    const int lane = t & 63;
    const int og   = lane & 15;          // output quad: o = 4*og .. 4*og+3
    const int fg   = lane >> 4;          // f stripe: f ≡ fg (mod 4)
    const int ec   = ecount;

    const float4 be4 = ((const float4*)b_eq)[og];
    const float4 wa  = ((const float4*)W_att)[og];
    const float  ba  = b_att[0];

    // shared sites2 partial: p2 = sum_{f in [64,128)} s2[f-64] * Weff[f][4og..]
    float4 p2 = make_float4(0.f, 0.f, 0.f, 0.f);
#pragma unroll
    for (int fi = 0; fi < 16; ++fi) {
        const int f  = 64 + 4 * fi + fg;
        const float  vf = s2[4 * fi + fg];
        const float4 wv = *(const float4*)&Weff[f][og * 4];
        p2.x += vf * wv.x; p2.y += vf * wv.y;
        p2.z += vf * wv.z; p2.w += vf * wv.w;
    }

    float4 oacc = make_float4(0.f, 0.f, 0.f, 0.f);

    for (int base = w * EB; base < ec; base += NW * EB) {
        const int nb = (ec - base < EB) ? (ec - base) : EB;

        // stage this batch's varying v entries: [sites1 row | bonds row]
        __builtin_amdgcn_wave_barrier();
#pragma unroll
        for (int j = 0; j < EB; ++j) {
            const int jj = j < nb ? j : nb - 1;    // clamp: pads reuse a valid edge
            const int e  = elist[base + jj];
            const int i1 = idx1[e];
            vs[w][j][lane] = sites1[((b * N1n + i1) << 6) + lane];
            if (lane < CBn) vs[w][j][CINn + lane] = bonds[(b * En + e) * CBn + lane];
        }
        __builtin_amdgcn_wave_barrier();

        float4 acc[EB];
#pragma unroll
        for (int j = 0; j < EB; ++j) acc[j] = p2;

        // matvec over the 96 varying f's; each Weff b128 feeds all EB edges
#pragma unroll
        for (int fi = 0; fi < 24; ++fi) {
            const int vsidx = 4 * fi + fg;
            const int f     = vsidx < CINn ? vsidx : vsidx + CINn;  // skip s2 band
            const float4 wv = *(const float4*)&Weff[f][og * 4];
#pragma unroll
            for (int j = 0; j < EB; ++j) {
                const float vf = vs[w][j][vsidx];
                acc[j].x += vf * wv.x; acc[j].y += vf * wv.y;
                acc[j].z += vf * wv.z; acc[j].w += vf * wv.w;
            }
        }
        __builtin_amdgcn_wave_barrier();

        // per-edge epilogue
#pragma unroll
        for (int j = 0; j < EB; ++j) {
            float4 a = acc[j];
#pragma unroll
            for (int m = 16; m <= 32; m <<= 1) {     // reduce the 4 f stripes
                a.x += __shfl_xor(a.x, m);
                a.y += __shfl_xor(a.y, m);
                a.z += __shfl_xor(a.z, m);
                a.w += __shfl_xor(a.w, m);
            }
            float4 lat;
            lat.x = a.x + be4.x; lat.x = lat.x > 0.f ? lat.x : NEG * lat.x;
            lat.y = a.y + be4.y; lat.y = lat.y > 0.f ? lat.y : NEG * lat.y;
            lat.z = a.z + be4.z; lat.z = lat.z > 0.f ? lat.z : NEG * lat.z;
            lat.w = a.w + be4.w; lat.w = lat.w > 0.f ? lat.w : NEG * lat.w;

            float part = lat.x * wa.x + lat.y * wa.y + lat.z * wa.z + lat.w * wa.w;
#pragma unroll
            for (int m = 1; m <= 8; m <<= 1) part += __shfl_xor(part, m);

            float att = 1.f / (1.f + expf(-(part + ba)));
            att *= (j < nb) ? 1.f : 0.f;             // mask clamp-padded edges
            oacc.x += att * lat.x;
            oacc.y += att * lat.y;
            oacc.z += att * lat.z;
            oacc.w += att * lat.w;
        }
    }

    if (fg == 0) *(float4*)&red[w][og * 4] = oacc;
    __syncthreads();

    // write this sub-block's 64-float partial into workspace
    if (t < On) {
        float s = 0.f;
#pragma unroll
        for (int q = 0; q < NW; ++q) s += red[q][t];
        ws[((size_t)bucket * SUBn + sub) * On + t] = s;
    }
}

// ---------------------------------------------------------------------------
// deterministic cross-sub reduction: out[bucket][o] = sum_sub ws[bucket][sub][o]
__global__ void __launch_bounds__(256)
reduce_kernel(const float* __restrict__ ws, float* __restrict__ out) {
    const int i = blockIdx.x * 256 + threadIdx.x;   // 0 .. Bn*Kn*On-1
    const int bucket = i >> 6;
    const int o      = i & (On - 1);
    const float* p = ws + (size_t)bucket * SUBn * On + o;
    float s01 = p[0]      + p[On];
    float s23 = p[2 * On] + p[3 * On];
    float s45 = p[4 * On] + p[5 * On];
    float s67 = p[6 * On] + p[7 * On];
    out[i] = (s01 + s23) + (s45 + s67);
}

// ---------------------------------------------------------------------------
extern "C" void kernel_launch(void* const* d_in, const int* in_sizes, int n_in,
                              void* d_out, int out_size, void* d_ws, size_t ws_size,
                              hipStream_t stream) {
    const float* sites1 = (const float*)d_in[0];
    const float* sites2 = (const float*)d_in[1];
    const float* bonds  = (const float*)d_in[2];
    const float* W_eq   = (const float*)d_in[3];
    const float* b_eq   = (const float*)d_in[4];
    const float* W_att  = (const float*)d_in[5];
    const float* b_att  = (const float*)d_in[6];
    /* d_in[7] = idx2_oh (unused — reduced algebraically) */
    const int*   idx1   = (const int*)d_in[8];
    const int*   idx2   = (const int*)d_in[9];
    const int*   perms1 = (const int*)d_in[10];
    const int*   perms2 = (const int*)d_in[11];
    float* out = (float*)d_out;
    float* ws  = (float*)d_ws;

    fused_kernel<<<Bn * Kn * SUBn, NT, 0, stream>>>(
        sites1, sites2, bonds, W_eq, b_eq, W_att, b_att,
        idx1, idx2, perms1, perms2, ws);
    reduce_kernel<<<(Bn * Kn * On) / 256, 256, 0, stream>>>(ws, out);
}